// Round 1
// baseline (469.407 us; speedup 1.0000x reference)
//
#include <hip/hip_runtime.h>

#define SD 64   // STATE_DIM
#define MD 32   // MEASURE_DIM

// ---------------------------------------------------------------------------
// Kernel A: single block. Computes K [64x32] and b [64] where
//   x_new = b + K @ z,  b = x_pred - K @ (H @ x_pred)
// All small-matrix algebra in fp32 with LDS staging. S is ~3I (diagonally
// dominant) so Gauss-Jordan without pivoting is numerically safe.
// ---------------------------------------------------------------------------
__global__ __launch_bounds__(256) void akf_prepare(
    const float* __restrict__ F, const float* __restrict__ H,
    const float* __restrict__ Q, const float* __restrict__ R,
    const float* __restrict__ P, const float* __restrict__ x,
    float* __restrict__ Kb)
{
    __shared__ float sT[SD * SD];    // F@P; later reused for PHt (64x32)
    __shared__ float sPp[SD * SD];   // P_pred
    __shared__ float sHP[MD * SD];   // H @ P_pred
    __shared__ float sAug[MD][2 * MD];  // [S | I] augmented for inversion
    __shared__ float sK[SD * MD];
    __shared__ float sxp[SD];
    __shared__ float sHx[MD];
    __shared__ float sfac[MD];
    __shared__ float spiv;

    const int tid = threadIdx.x;

    // x_pred = F @ x
    if (tid < SD) {
        float a = 0.f;
        for (int k = 0; k < SD; ++k) a += F[tid * SD + k] * x[k];
        sxp[tid] = a;
    }
    // T = F @ P
    for (int idx = tid; idx < SD * SD; idx += 256) {
        int i = idx >> 6, j = idx & 63;
        float a = 0.f;
        for (int k = 0; k < SD; ++k) a += F[i * SD + k] * P[k * SD + j];
        sT[idx] = a;
    }
    __syncthreads();

    // P_pred = T @ F^T + Q
    for (int idx = tid; idx < SD * SD; idx += 256) {
        int i = idx >> 6, j = idx & 63;
        float a = Q[idx];
        for (int k = 0; k < SD; ++k) a += sT[i * SD + k] * F[j * SD + k];
        sPp[idx] = a;
    }
    __syncthreads();

    // HP = H @ P_pred  (32x64);  Hx = H @ x_pred
    for (int idx = tid; idx < MD * SD; idx += 256) {
        int i = idx >> 6, j = idx & 63;
        float a = 0.f;
        for (int k = 0; k < SD; ++k) a += H[i * SD + k] * sPp[k * SD + j];
        sHP[idx] = a;
    }
    if (tid < MD) {
        float a = 0.f;
        for (int k = 0; k < SD; ++k) a += H[tid * SD + k] * sxp[k];
        sHx[tid] = a;
    }
    __syncthreads();

    // S = HP @ H^T + R; build augmented [S | I]
    for (int idx = tid; idx < MD * MD; idx += 256) {
        int i = idx >> 5, j = idx & 31;
        float a = R[idx];
        for (int k = 0; k < SD; ++k) a += sHP[i * SD + k] * H[j * SD + k];
        sAug[i][j] = a;
        sAug[i][MD + j] = (i == j) ? 1.f : 0.f;
    }
    __syncthreads();

    // Gauss-Jordan elimination (no pivot search; S ~ 3I)
    for (int kp = 0; kp < MD; ++kp) {
        if (tid == 0) spiv = 1.f / sAug[kp][kp];
        __syncthreads();
        if (tid < 2 * MD) sAug[kp][tid] *= spiv;
        __syncthreads();
        if (tid < MD) sfac[tid] = (tid == kp) ? 0.f : sAug[tid][kp];
        __syncthreads();
        for (int idx = tid; idx < MD * 2 * MD; idx += 256) {
            int i = idx >> 6, j = idx & 63;
            if (i != kp) sAug[i][j] -= sfac[i] * sAug[kp][j];
        }
        __syncthreads();
    }

    // PHt = P_pred @ H^T  (64x32), reuse sT
    for (int idx = tid; idx < SD * MD; idx += 256) {
        int i = idx >> 5, j = idx & 31;
        float a = 0.f;
        for (int k = 0; k < SD; ++k) a += sPp[i * SD + k] * H[j * SD + k];
        sT[idx] = a;
    }
    __syncthreads();

    // K = PHt @ Sinv  (64x32); Sinv is right half of sAug
    for (int idx = tid; idx < SD * MD; idx += 256) {
        int i = idx >> 5, j = idx & 31;
        float a = 0.f;
        for (int k = 0; k < MD; ++k) a += sT[i * MD + k] * sAug[k][MD + j];
        sK[idx] = a;
        Kb[idx] = a;
    }
    __syncthreads();

    // b = x_pred - K @ Hx
    if (tid < SD) {
        float a = sxp[tid];
        for (int j = 0; j < MD; ++j) a -= sK[tid * MD + j] * sHx[j];
        Kb[SD * MD + tid] = a;
    }
}

// ---------------------------------------------------------------------------
// Kernel B: out[i, n] = b[i] + sum_j K[i][j] * z[j, n]
// Each thread handles 4 consecutive columns (float4). K + b staged in LDS;
// K reads are wave-uniform broadcasts via ds_read_b128 (conflict-free).
// Memory-bound: 384 MB traffic -> ~61 us floor at 6.3 TB/s.
// ---------------------------------------------------------------------------
__global__ __launch_bounds__(256) void akf_apply(
    const float* __restrict__ z, const float* __restrict__ Kb,
    float* __restrict__ out, int N)
{
    __shared__ float sK[SD * MD];
    __shared__ float sb[SD];

    const int tid = threadIdx.x;
    for (int idx = tid; idx < SD * MD; idx += 256) sK[idx] = Kb[idx];
    if (tid < SD) sb[tid] = Kb[SD * MD + tid];
    __syncthreads();

    const int c = (blockIdx.x * 256 + tid) * 4;
    if (c >= N) return;

    float4 zv[MD];
#pragma unroll
    for (int j = 0; j < MD; ++j)
        zv[j] = *(const float4*)(z + (size_t)j * N + c);

#pragma unroll 2
    for (int i = 0; i < SD; ++i) {
        const float bi = sb[i];
        float4 acc = make_float4(bi, bi, bi, bi);
#pragma unroll
        for (int j = 0; j < MD; j += 4) {
            const float4 k4 = *(const float4*)(&sK[i * MD + j]);
            acc.x = fmaf(k4.x, zv[j].x, acc.x);
            acc.y = fmaf(k4.x, zv[j].y, acc.y);
            acc.z = fmaf(k4.x, zv[j].z, acc.z);
            acc.w = fmaf(k4.x, zv[j].w, acc.w);
            acc.x = fmaf(k4.y, zv[j + 1].x, acc.x);
            acc.y = fmaf(k4.y, zv[j + 1].y, acc.y);
            acc.z = fmaf(k4.y, zv[j + 1].z, acc.z);
            acc.w = fmaf(k4.y, zv[j + 1].w, acc.w);
            acc.x = fmaf(k4.z, zv[j + 2].x, acc.x);
            acc.y = fmaf(k4.z, zv[j + 2].y, acc.y);
            acc.z = fmaf(k4.z, zv[j + 2].z, acc.z);
            acc.w = fmaf(k4.z, zv[j + 2].w, acc.w);
            acc.x = fmaf(k4.w, zv[j + 3].x, acc.x);
            acc.y = fmaf(k4.w, zv[j + 3].y, acc.y);
            acc.z = fmaf(k4.w, zv[j + 3].z, acc.z);
            acc.w = fmaf(k4.w, zv[j + 3].w, acc.w);
        }
        *(float4*)(out + (size_t)i * N + c) = acc;
    }
}

extern "C" void kernel_launch(void* const* d_in, const int* in_sizes, int n_in,
                              void* d_out, int out_size, void* d_ws, size_t ws_size,
                              hipStream_t stream)
{
    // setup_inputs order: z, F, H, Q, R, P, x  (all float32)
    const float* z = (const float*)d_in[0];
    const float* F = (const float*)d_in[1];
    const float* H = (const float*)d_in[2];
    const float* Q = (const float*)d_in[3];
    const float* R = (const float*)d_in[4];
    const float* P = (const float*)d_in[5];
    const float* x = (const float*)d_in[6];
    float* out = (float*)d_out;
    float* Kb = (float*)d_ws;   // K (64*32 floats) then b (64 floats)

    const int N = in_sizes[0] / MD;   // 1048576

    akf_prepare<<<1, 256, 0, stream>>>(F, H, Q, R, P, x, Kb);

    const int cols_per_block = 256 * 4;
    const int nblocks = (N + cols_per_block - 1) / cols_per_block;
    akf_apply<<<nblocks, 256, 0, stream>>>(z, Kb, out, N);
}

// Round 2
// 399.472 us; speedup vs baseline: 1.1751x; 1.1751x over previous
//
#include <hip/hip_runtime.h>

#define SD 64   // STATE_DIM
#define MD 32   // MEASURE_DIM

typedef float f32x4 __attribute__((ext_vector_type(4)));

// ---------------------------------------------------------------------------
// Kernel A: one block, 1024 threads. Computes K [64x32] and b [64]:
//   x_new = b + K @ z,  b = x_pred - K @ (H @ x_pred)
// All matmul operands staged in LDS with conflict-free layouts:
//   - transposed copies (sFt, sHt) for column-access patterns
//   - padded strides 68 / 36 keep float4 reads 16B-aligned AND bank-spread
// S^{-1} via Gauss-Jordan inside wave 0 using __shfl (no barriers; S ~ 3I is
// diagonally dominant so no pivoting needed).
// ---------------------------------------------------------------------------
__global__ __launch_bounds__(1024) void akf_prepare(
    const float* __restrict__ F, const float* __restrict__ H,
    const float* __restrict__ Q, const float* __restrict__ R,
    const float* __restrict__ P, const float* __restrict__ x,
    float* __restrict__ Kb)
{
    __shared__ __align__(16) float sF [SD * SD];    // F row-major (broadcast reads)
    __shared__ __align__(16) float sFt[SD * 68];    // sFt[k*68+j] = F[j][k]
    __shared__ __align__(16) float sP [SD * SD];    // P row-major
    __shared__ __align__(16) float sT [SD * 68];    // T = F@P
    __shared__ __align__(16) float sPp[SD * 68];    // P_pred
    __shared__ __align__(16) float sH [MD * SD];    // H row-major (broadcast reads)
    __shared__ __align__(16) float sHt[SD * 36];    // sHt[k*36+j] = H[j][k]
    __shared__ __align__(16) float sA [SD * 36];    // A = P_pred @ H^T
    __shared__ __align__(16) float sS [MD * 33];    // S
    __shared__ __align__(16) float sSi[MD * 36];    // S^{-1}
    __shared__ __align__(16) float sK [SD * 36];    // K
    __shared__ float sx[SD], sxp[SD], sHx[MD];

    const int tid = threadIdx.x;

    // ---- stage inputs (coalesced reads; transposed copies for column access)
    for (int idx = tid; idx < SD * SD; idx += 1024) {
        float f = F[idx], p = P[idx];
        int i = idx >> 6, j = idx & 63;
        sF[idx] = f;
        sFt[j * 68 + i] = f;
        sP[idx] = p;
    }
    for (int idx = tid; idx < MD * SD; idx += 1024) {
        float h = H[idx];
        int j = idx >> 6, k = idx & 63;
        sH[idx] = h;
        sHt[k * 36 + j] = h;
    }
    if (tid < SD) sx[tid] = x[tid];
    __syncthreads();

    // ---- x_pred = F @ x  (column-major F reads via sFt: conflict-free)
    if (tid < SD) {
        float a = 0.f;
        for (int k = 0; k < SD; ++k) a = fmaf(sFt[k * 68 + tid], sx[k], a);
        sxp[tid] = a;
    }

    // ---- T = F @ P : thread -> (i, j0..j0+3)
    {
        const int i = tid >> 4, j0 = (tid & 15) * 4;
        f32x4 acc = {0.f, 0.f, 0.f, 0.f};
        for (int k = 0; k < SD; ++k) {
            const float f = sF[i * 64 + k];                     // wave broadcast
            const f32x4 p4 = *(const f32x4*)&sP[k * 64 + j0];   // b128, bank-spread
            acc.x = fmaf(f, p4.x, acc.x);
            acc.y = fmaf(f, p4.y, acc.y);
            acc.z = fmaf(f, p4.z, acc.z);
            acc.w = fmaf(f, p4.w, acc.w);
        }
        *(f32x4*)&sT[i * 68 + j0] = acc;
    }
    __syncthreads();

    // ---- P_pred = T @ F^T + Q
    {
        const int i = tid >> 4, j0 = (tid & 15) * 4;
        f32x4 acc = *(const f32x4*)&Q[i * 64 + j0];
        for (int k = 0; k < SD; ++k) {
            const float t = sT[i * 68 + k];
            const f32x4 f4 = *(const f32x4*)&sFt[k * 68 + j0];
            acc.x = fmaf(t, f4.x, acc.x);
            acc.y = fmaf(t, f4.y, acc.y);
            acc.z = fmaf(t, f4.z, acc.z);
            acc.w = fmaf(t, f4.w, acc.w);
        }
        *(f32x4*)&sPp[i * 68 + j0] = acc;
    }
    __syncthreads();

    // ---- Hx = H @ x_pred (tid<32) and A = P_pred @ H^T (tid<512)
    if (tid < MD) {
        float a = 0.f;
        for (int k = 0; k < SD; ++k) a = fmaf(sHt[k * 36 + tid], sxp[k], a);
        sHx[tid] = a;
    }
    if (tid < 512) {
        const int i = tid >> 3, j0 = (tid & 7) * 4;
        f32x4 acc = {0.f, 0.f, 0.f, 0.f};
        for (int k = 0; k < SD; ++k) {
            const float p = sPp[i * 68 + k];
            const f32x4 h4 = *(const f32x4*)&sHt[k * 36 + j0];
            acc.x = fmaf(p, h4.x, acc.x);
            acc.y = fmaf(p, h4.y, acc.y);
            acc.z = fmaf(p, h4.z, acc.z);
            acc.w = fmaf(p, h4.w, acc.w);
        }
        *(f32x4*)&sA[i * 36 + j0] = acc;
    }
    __syncthreads();

    // ---- S = H @ A + R : one output per thread
    {
        const int i = tid >> 5, j = tid & 31;
        float a = R[i * 32 + j];
        for (int k = 0; k < SD; ++k) a = fmaf(sH[i * 64 + k], sA[k * 36 + j], a);
        sS[i * 33 + j] = a;
    }
    __syncthreads();

    // ---- S^{-1} via Gauss-Jordan on wave 0, lane l owns aug column l of [S|I]
    if (tid < 64) {
        float col[MD];
#pragma unroll
        for (int i = 0; i < MD; ++i)
            col[i] = (tid < MD) ? sS[i * 33 + tid] : ((i == tid - MD) ? 1.f : 0.f);
#pragma unroll
        for (int kp = 0; kp < MD; ++kp) {
            const float piv = __shfl(col[kp], kp);
            const float r = 1.0f / piv;
            col[kp] *= r;                 // scale pivot row
            const float pr = col[kp];
#pragma unroll
            for (int i = 0; i < MD; ++i) {
                if (i == kp) continue;
                const float f = __shfl(col[i], kp);   // aug[i][kp] (pre-update)
                col[i] = fmaf(-f, pr, col[i]);
            }
        }
        if (tid >= MD) {
            const int j = tid - MD;
#pragma unroll
            for (int i = 0; i < MD; ++i) sSi[i * 36 + j] = col[i];
        }
    }
    __syncthreads();

    // ---- K = A @ S^{-1} (tid<512), write to LDS + global
    if (tid < 512) {
        const int i = tid >> 3, j0 = (tid & 7) * 4;
        f32x4 acc = {0.f, 0.f, 0.f, 0.f};
        for (int k = 0; k < MD; ++k) {
            const float a = sA[i * 36 + k];
            const f32x4 s4 = *(const f32x4*)&sSi[k * 36 + j0];
            acc.x = fmaf(a, s4.x, acc.x);
            acc.y = fmaf(a, s4.y, acc.y);
            acc.z = fmaf(a, s4.z, acc.z);
            acc.w = fmaf(a, s4.w, acc.w);
        }
        *(f32x4*)&sK[i * 36 + j0] = acc;
        *(f32x4*)&Kb[i * MD + j0] = acc;
    }
    __syncthreads();

    // ---- b = x_pred - K @ Hx
    if (tid < SD) {
        float a = sxp[tid];
        for (int j = 0; j < MD; ++j) a = fmaf(-sK[tid * 36 + j], sHx[j], a);
        Kb[SD * MD + tid] = a;
    }
}

// ---------------------------------------------------------------------------
// Kernel B: out[i, c] = b[i] + sum_j K[i][j] * z[j, c]
// K/b reads have NO threadIdx dependence -> compiler scalarizes to s_load
// (scalar cache broadcast, zero LDS traffic). z/out streamed nontemporal.
// 512 blocks x 256 thr, 2 column-groups of float4 per thread:
// 2 blocks/CU all co-resident (no tail round). Memory-bound:
// 384 MB @ ~6 TB/s -> ~64 us floor.
// ---------------------------------------------------------------------------
__global__ __launch_bounds__(256) void akf_apply(
    const float* __restrict__ z, const float* __restrict__ Kb,
    float* __restrict__ out, int N)
{
    const int base = blockIdx.x * (256 * 8) + threadIdx.x * 4;

#pragma unroll 1   // keep groups sequential: 2x zv[32] live would spill
    for (int g = 0; g < 2; ++g) {
        const int c = base + g * (256 * 4);
        if (c >= N) continue;

        f32x4 zv[MD];
#pragma unroll
        for (int j = 0; j < MD; ++j)
            zv[j] = __builtin_nontemporal_load((const f32x4*)(z + (size_t)j * N + c));

#pragma unroll 4
        for (int i = 0; i < SD; ++i) {
            const float bi = Kb[SD * MD + i];          // uniform -> s_load
            f32x4 acc = {bi, bi, bi, bi};
#pragma unroll
            for (int j = 0; j < MD; ++j) {
                const float k = Kb[i * MD + j];        // uniform -> s_load
                acc.x = fmaf(k, zv[j].x, acc.x);
                acc.y = fmaf(k, zv[j].y, acc.y);
                acc.z = fmaf(k, zv[j].z, acc.z);
                acc.w = fmaf(k, zv[j].w, acc.w);
            }
            __builtin_nontemporal_store(acc, (f32x4*)(out + (size_t)i * N + c));
        }
    }
}

extern "C" void kernel_launch(void* const* d_in, const int* in_sizes, int n_in,
                              void* d_out, int out_size, void* d_ws, size_t ws_size,
                              hipStream_t stream)
{
    // setup_inputs order: z, F, H, Q, R, P, x  (all float32)
    const float* z = (const float*)d_in[0];
    const float* F = (const float*)d_in[1];
    const float* H = (const float*)d_in[2];
    const float* Q = (const float*)d_in[3];
    const float* R = (const float*)d_in[4];
    const float* P = (const float*)d_in[5];
    const float* x = (const float*)d_in[6];
    float* out = (float*)d_out;
    float* Kb = (float*)d_ws;   // K (64*32 floats) then b (64 floats)

    const int N = in_sizes[0] / MD;   // 1048576

    akf_prepare<<<1, 1024, 0, stream>>>(F, H, Q, R, P, x, Kb);

    const int cols_per_block = 256 * 8;   // 2 float4 groups per thread
    const int nblocks = (N + cols_per_block - 1) / cols_per_block;
    akf_apply<<<nblocks, 256, 0, stream>>>(z, Kb, out, N);
}